// Round 6
// baseline (228.158 us; speedup 1.0000x reference)
//
#include <hip/hip_runtime.h>
#include <hip/hip_bf16.h>

#define LN_EPS 1e-5f

static __device__ __forceinline__ float readlane_f(float v, int lane) {
    return __int_as_float(__builtin_amdgcn_readlane(__float_as_int(v), lane));
}
// v_writelane_b32: set lane `lane_imm` of dst to uniform value `val`.
// Source must be SGPR-resident (readlane results qualify).
static __device__ __forceinline__ void writelane_f(int& dst, float val, int lane_imm) {
    asm volatile("v_writelane_b32 %0, %1, %2"
                 : "+v"(dst)
                 : "s"(__float_as_int(val)), "i"(lane_imm));
}

// ---------------------------------------------------------------------------
// Kernel A: per-token-id key table. key[v] = LN(e_v + FF(e_v)), v in [0,64).
// ---------------------------------------------------------------------------
__global__ __launch_bounds__(64) void build_keys(
    const float* __restrict__ embed,   // 64x64
    const float* __restrict__ w1,      // 64x128
    const float* __restrict__ b1,      // 128
    const float* __restrict__ w2,      // 128x64
    const float* __restrict__ b2,      // 64
    const float* __restrict__ lnw,     // 64
    const float* __restrict__ lnb,     // 64
    float* __restrict__ keytab)        // 64x64 out
{
    const int v = blockIdx.x, lane = threadIdx.x;
    __shared__ float se[64];
    __shared__ float sh[128];
    se[lane] = embed[v * 64 + lane];
    __syncthreads();
    float h0 = b1[lane];
    float h1 = b1[lane + 64];
    #pragma unroll 8
    for (int i = 0; i < 64; ++i) {
        float e = se[i];
        h0 = fmaf(e, w1[i * 128 + lane], h0);
        h1 = fmaf(e, w1[i * 128 + lane + 64], h1);
    }
    sh[lane]      = fmaxf(h0, 0.f);
    sh[lane + 64] = fmaxf(h1, 0.f);
    __syncthreads();
    float acc = b2[lane];
    #pragma unroll 8
    for (int j = 0; j < 128; ++j)
        acc = fmaf(sh[j], w2[j * 64 + lane], acc);
    float pre = se[lane] + acc;
    float sum = pre;
    #pragma unroll
    for (int off = 32; off >= 1; off >>= 1) sum += __shfl_xor(sum, off, 64);
    float mu  = sum * (1.f / 64.f);
    float dev = pre - mu;
    float sq  = dev * dev;
    #pragma unroll
    for (int off = 32; off >= 1; off >>= 1) sq += __shfl_xor(sq, off, 64);
    float var = sq * (1.f / 64.f);
    float key = dev * (1.f / sqrtf(var + LN_EPS)) * lnw[lane] + lnb[lane];
    keytab[v * 64 + lane] = key;
}

// ---------------------------------------------------------------------------
// Kernel B: Gram tables (Ghat stored NEGATED) + fused output weight.
// ---------------------------------------------------------------------------
__global__ __launch_bounds__(64) void build_tables(
    const float* __restrict__ keytab,
    const float* __restrict__ read_w,
    const float* __restrict__ read_b,
    const float* __restrict__ out_w,
    const float* __restrict__ out_b,
    float* __restrict__ Gg,
    float* __restrict__ GhatN,   // negated: -beta_w * G[w][u]
    float* __restrict__ Wc,
    float* __restrict__ biasv)
{
    const int w = blockIdx.x, lane = threadIdx.x;
    __shared__ float sk[64 * 65];
    __shared__ float srw[64];
    #pragma unroll 8
    for (int r = 0; r < 64; ++r) sk[r * 65 + lane] = keytab[r * 64 + lane];
    srw[lane] = read_w[w * 64 + lane];
    __syncthreads();
    float g = 0.f;
    #pragma unroll 8
    for (int i = 0; i < 64; ++i)
        g = fmaf(sk[w * 65 + i], sk[lane * 65 + i], g);
    float gww  = readlane_f(g, w);
    float beta = 1.f / (gww + 1e-6f);
    Gg[w * 64 + lane]    = g;
    GhatN[w * 64 + lane] = -(beta * g);
    float acc = 0.f;
    #pragma unroll 8
    for (int j = 0; j < 64; ++j)
        acc = fmaf(srw[j], out_w[j * 64 + lane], acc);
    Wc[w * 64 + lane] = acc;
    if (w == 0) {
        float bacc = out_b[lane];
        #pragma unroll 8
        for (int j = 0; j < 64; ++j)
            bacc = fmaf(read_b[j], out_w[j * 64 + lane], bacc);
        biasv[lane] = bacc;
    }
}

// ---------------------------------------------------------------------------
// Kernel C: dual-space backward delta scan, TWO BATCHES PER WAVE.
//
// Evidence (r4: pairing +13cy despite -1 round-trip; r5: depth 9 vs 21 ~=):
// the wave is issue+dependency-shadow bound; ~16cy/token of scoreboard
// stall on fmac(d)->readlane->fmac has NOTHING to fill it at 1 wave/CU.
// Fix: interleave two INDEPENDENT batch chains in one wave. Batch B's
// issue fills batch A's dependency shadows and vice versa. Per-batch body
// is the proven 49cy/token single-step structure, queue depth 9 (2x21
// would blow the SGPR budget; r5 showed depth is a ~6% effect).
// Per step & batch: s_t = d[w_t]; d += s_t*GhatN[w_t]; pack s_t; refill.
// ---------------------------------------------------------------------------
__global__ __launch_bounds__(64) void delta_scan(
    const int*   __restrict__ seq,     // B x 4096
    const float* __restrict__ Gg,      // 64x64
    const float* __restrict__ GhatN,   // 64x64 (negated)
    const float* __restrict__ keytab,  // 64x64
    const float* __restrict__ Wc,      // 64x64
    const float* __restrict__ biasv,   // 64
    float* __restrict__ out)           // B x 64
{
    const int lane = threadIdx.x;
    const int bA   = blockIdx.x * 2;      // this wave handles batches bA, bA+1
    const int bB   = bA + 1;
    __shared__ float sG[64 * 64];   // negated Ghat rows (shared by both batches)
    __shared__ float scA[64];       // c bins, batch A
    __shared__ float scB[64];       // c bins, batch B
    __shared__ float sCtxA[64];
    __shared__ float sCtxB[64];
    #pragma unroll 8
    for (int r = 0; r < 64; ++r) sG[r * 64 + lane] = GhatN[r * 64 + lane];
    scA[lane] = 0.f;
    scB[lane] = 0.f;
    const int* seqA = seq + (size_t)bA * 4096;
    const int* seqB = seq + (size_t)bB * 4096;
    float dA = Gg[seqA[4095] * 64 + lane];   // d_v = G[w_query][v]
    float dB = Gg[seqB[4095] * 64 + lane];
    __syncthreads();

    int vSA = 0, vSB = 0;              // packed s_t bits, lane = j (lane 63 = 0)
    int vcurA = seqA[64 * 63 + lane];  // top chunk tokens: t = 4032+lane
    int vcurB = seqB[64 * 63 + lane];
    int   wqA[9], wqB[9];              // rotating token queues (SGPR, uniform)
    float qA[9],  qB[9];               // rotating GhatN-row queues (LDS prefetch)
    #pragma unroll
    for (int s = 0; s < 9; ++s) {
        wqA[s] = __builtin_amdgcn_readlane(vcurA, 62 - s);
        qA[s]  = sG[wqA[s] * 64 + lane];
        wqB[s] = __builtin_amdgcn_readlane(vcurB, 62 - s);
        qB[s]  = sG[wqB[s] * 64 + lane];
    }

    #pragma unroll 1
    for (int blk = 64; blk >= 0; --blk) {
        int vnextA = (blk > 0) ? seqA[(blk - 1) * 63 + lane] : vcurA;
        int vnextB = (blk > 0) ? seqB[(blk - 1) * 63 + lane] : vcurB;
        #pragma unroll
        for (int j = 62; j >= 0; --j) {        // t = blk*63 + j, descending
            const int slot = (62 - j) % 9;
            const int jl   = j - 9;            // compile-time after unroll
            // ---- batch A step ----
            {
                int   w0 = wqA[slot];
                float p  = readlane_f(dA, w0);       // s_t = d[w_t]
                dA = fmaf(p, qA[slot], dA);          // d += s_t * GhatN[w_t]
                writelane_f(vSA, p, j);              // pack s_t at lane j
                int wn = (jl >= 0) ? __builtin_amdgcn_readlane(vcurA, jl)
                                   : __builtin_amdgcn_readlane(vnextA, jl + 63);
                wqA[slot] = wn;
                qA[slot]  = sG[wn * 64 + lane];      // prefetch row (used in 9 steps)
            }
            // ---- batch B step (independent chain; fills A's stall shadow) ----
            {
                int   w0 = wqB[slot];
                float p  = readlane_f(dB, w0);
                dB = fmaf(p, qB[slot], dB);
                writelane_f(vSB, p, j);
                int wn = (jl >= 0) ? __builtin_amdgcn_readlane(vcurB, jl)
                                   : __builtin_amdgcn_readlane(vnextB, jl + 63);
                wqB[slot] = wn;
                qB[slot]  = sG[wn * 64 + lane];
            }
        }
        // scatter each chunk's 63 s-values into c bins (lane 63 adds 0.0)
        atomicAdd(&scA[vcurA & 63], __int_as_float(vSA));
        atomicAdd(&scB[vcurB & 63], __int_as_float(vSB));
        vSA = 0; vSB = 0;
        vcurA = vnextA;
        vcurB = vnextB;
    }
    __syncthreads();

    // ctx = sum_v c_v * key_v ; out = ctx @ Wc + bias   (both batches)
    float ctxA = 0.f, ctxB = 0.f;
    #pragma unroll 8
    for (int v = 0; v < 64; ++v) {
        float k = keytab[v * 64 + lane];
        ctxA = fmaf(scA[v], k, ctxA);
        ctxB = fmaf(scB[v], k, ctxB);
    }
    sCtxA[lane] = ctxA;
    sCtxB[lane] = ctxB;
    __syncthreads();
    float oA = biasv[lane], oB = oA;
    #pragma unroll 8
    for (int i = 0; i < 64; ++i) {
        float w = Wc[i * 64 + lane];
        oA = fmaf(sCtxA[i], w, oA);
        oB = fmaf(sCtxB[i], w, oB);
    }
    out[(size_t)bA * 64 + lane] = oA;
    out[(size_t)bB * 64 + lane] = oB;
}

extern "C" void kernel_launch(void* const* d_in, const int* in_sizes, int n_in,
                              void* d_out, int out_size, void* d_ws, size_t ws_size,
                              hipStream_t stream) {
    const int*   seq    = (const int*)d_in[0];
    const float* embed  = (const float*)d_in[1];
    const float* ff_w1  = (const float*)d_in[2];
    const float* ff_b1  = (const float*)d_in[3];
    const float* ff_w2  = (const float*)d_in[4];
    const float* ff_b2  = (const float*)d_in[5];
    const float* ln_w   = (const float*)d_in[6];
    const float* ln_b   = (const float*)d_in[7];
    const float* read_w = (const float*)d_in[8];
    const float* read_b = (const float*)d_in[9];
    const float* out_w  = (const float*)d_in[10];
    const float* out_b  = (const float*)d_in[11];
    float* out = (float*)d_out;

    float* wsf    = (float*)d_ws;
    float* keytab = wsf;            // 4096
    float* Gg     = wsf + 4096;     // 4096
    float* GhatN  = wsf + 8192;     // 4096
    float* Wc     = wsf + 12288;    // 4096
    float* biasv  = wsf + 16384;    // 64

    build_keys<<<64, 64, 0, stream>>>(embed, ff_w1, ff_b1, ff_w2, ff_b2, ln_w, ln_b, keytab);
    build_tables<<<64, 64, 0, stream>>>(keytab, read_w, read_b, out_w, out_b,
                                        Gg, GhatN, Wc, biasv);
    delta_scan<<<128, 64, 0, stream>>>(seq, Gg, GhatN, keytab, Wc, biasv, out);
}

// Round 8
// 200.971 us; speedup vs baseline: 1.1353x; 1.1353x over previous
//
#include <hip/hip_runtime.h>
#include <hip/hip_bf16.h>

#define LN_EPS 1e-5f

static __device__ __forceinline__ float readlane_f(float v, int lane) {
    return __int_as_float(__builtin_amdgcn_readlane(__float_as_int(v), lane));
}
static __device__ __forceinline__ float readlane_fs(float v, int slane) {
    return __int_as_float(__builtin_amdgcn_readlane(__float_as_int(v), slane));
}
// v_writelane_b32: set lane `lane_imm` of dst to uniform value `val`.
// Source must be SGPR-resident (readlane results qualify).
static __device__ __forceinline__ void writelane_f(int& dst, float val, int lane_imm) {
    asm volatile("v_writelane_b32 %0, %1, %2"
                 : "+v"(dst)
                 : "s"(__float_as_int(val)), "i"(lane_imm));
}

// ---------------------------------------------------------------------------
// Kernel A: per-token-id key table. key[v] = LN(e_v + FF(e_v)), v in [0,64).
// ---------------------------------------------------------------------------
__global__ __launch_bounds__(64) void build_keys(
    const float* __restrict__ embed,   // 64x64
    const float* __restrict__ w1,      // 64x128
    const float* __restrict__ b1,      // 128
    const float* __restrict__ w2,      // 128x64
    const float* __restrict__ b2,      // 64
    const float* __restrict__ lnw,     // 64
    const float* __restrict__ lnb,     // 64
    float* __restrict__ keytab)        // 64x64 out
{
    const int v = blockIdx.x, lane = threadIdx.x;
    __shared__ float se[64];
    __shared__ float sh[128];
    se[lane] = embed[v * 64 + lane];
    __syncthreads();
    float h0 = b1[lane];
    float h1 = b1[lane + 64];
    #pragma unroll 8
    for (int i = 0; i < 64; ++i) {
        float e = se[i];
        h0 = fmaf(e, w1[i * 128 + lane], h0);
        h1 = fmaf(e, w1[i * 128 + lane + 64], h1);
    }
    sh[lane]      = fmaxf(h0, 0.f);
    sh[lane + 64] = fmaxf(h1, 0.f);
    __syncthreads();
    float acc = b2[lane];
    #pragma unroll 8
    for (int j = 0; j < 128; ++j)
        acc = fmaf(sh[j], w2[j * 64 + lane], acc);
    float pre = se[lane] + acc;
    float sum = pre;
    #pragma unroll
    for (int off = 32; off >= 1; off >>= 1) sum += __shfl_xor(sum, off, 64);
    float mu  = sum * (1.f / 64.f);
    float dev = pre - mu;
    float sq  = dev * dev;
    #pragma unroll
    for (int off = 32; off >= 1; off >>= 1) sq += __shfl_xor(sq, off, 64);
    float var = sq * (1.f / 64.f);
    float key = dev * (1.f / sqrtf(var + LN_EPS)) * lnw[lane] + lnb[lane];
    keytab[v * 64 + lane] = key;
}

// ---------------------------------------------------------------------------
// Kernel B: Gram tables (Ghat stored NEGATED) + fused output weight.
// ---------------------------------------------------------------------------
__global__ __launch_bounds__(64) void build_tables(
    const float* __restrict__ keytab,
    const float* __restrict__ read_w,
    const float* __restrict__ read_b,
    const float* __restrict__ out_w,
    const float* __restrict__ out_b,
    float* __restrict__ Gg,
    float* __restrict__ GhatN,   // negated: -beta_w * G[w][u]
    float* __restrict__ Wc,
    float* __restrict__ biasv)
{
    const int w = blockIdx.x, lane = threadIdx.x;
    __shared__ float sk[64 * 65];
    __shared__ float srw[64];
    #pragma unroll 8
    for (int r = 0; r < 64; ++r) sk[r * 65 + lane] = keytab[r * 64 + lane];
    srw[lane] = read_w[w * 64 + lane];
    __syncthreads();
    float g = 0.f;
    #pragma unroll 8
    for (int i = 0; i < 64; ++i)
        g = fmaf(sk[w * 65 + i], sk[lane * 65 + i], g);
    float gww  = readlane_f(g, w);
    float beta = 1.f / (gww + 1e-6f);
    Gg[w * 64 + lane]    = g;
    GhatN[w * 64 + lane] = -(beta * g);
    float acc = 0.f;
    #pragma unroll 8
    for (int j = 0; j < 64; ++j)
        acc = fmaf(srw[j], out_w[j * 64 + lane], acc);
    Wc[w * 64 + lane] = acc;
    if (w == 0) {
        float bacc = out_b[lane];
        #pragma unroll 8
        for (int j = 0; j < 64; ++j)
            bacc = fmaf(read_b[j], out_w[j * 64 + lane], bacc);
        biasv[lane] = bacc;
    }
}

// ---------------------------------------------------------------------------
// Kernel C: dual-space backward delta scan, 3-TOKEN COMPRESSED GROUPS.
//
// Serial recurrence: s_t = d[w_t]; d += s_t * GhatN[w_t]; c[w_t] += s_t.
// Evidence r4-r6: per-step cost = ~17cy issue + ~32cy readlane round-trip
// stall; the round-trip is the floor. Fix: ONE round-trip per 3 tokens.
//   b_i = d[w_i]  (3 PARALLEL readlanes of the same d)
//   s0 = b0
//   s1 = b1 + A10*s0                    A_ij = GhatN[w_i][w_j]
//   s2 = (b2 + A20*s0) + A21*s1
//   d += s0*R0 + s1*R1 + s2*R2
// Same fma chain as the serial scan. A-entries are extracted OFF-CHAIN by
// readlanes from rows already in the rotating prefetch queue (no LDS addr
// math). s1,s2 stay VGPR-uniform and are packed with v_cmp+v_cndmask
// (pure VALU -- avoids r4's VALU->SALU->writelane hazard); s0 is SGPR
// (readlane result) and uses writelane directly.
// Queue: 3 rotating slots x 3 rows; refill for group gg+3 (9 tokens ahead);
// A for group gg+1 extracted during gg. 63 = 21 groups x 3 per chunk keeps
// the proven vcur/vS/atomicAdd chunk-scatter structure unchanged.
// ---------------------------------------------------------------------------
__global__ __launch_bounds__(64) void delta_scan(
    const int*   __restrict__ seq,     // B x 4096
    const float* __restrict__ Gg,      // 64x64
    const float* __restrict__ GhatN,   // 64x64 (negated)
    const float* __restrict__ keytab,  // 64x64
    const float* __restrict__ Wc,      // 64x64
    const float* __restrict__ biasv,   // 64
    float* __restrict__ out)           // B x 64
{
    const int lane = threadIdx.x;
    const int b    = blockIdx.x;
    __shared__ float sG[64 * 64];   // negated Ghat rows
    __shared__ float sc[64];        // c bins
    __shared__ float sCtx[64];
    #pragma unroll 8
    for (int r = 0; r < 64; ++r) sG[r * 64 + lane] = GhatN[r * 64 + lane];
    sc[lane] = 0.f;
    const int* seqb = seq + (size_t)b * 4096;
    float d = Gg[seqb[4095] * 64 + lane];   // d_v = G[w_query][v]
    __syncthreads();

    int vS = 0;                       // packed s_t bits, lane = j (lane 63 stays 0)
    int vcur = seqb[64 * 63 + lane];  // top chunk tokens: t = 4032+lane
    int   wq[3][3];                   // rotating token queue (SGPR, uniform)
    float rq[3][3];                   // rotating GhatN-row queue (LDS prefetch)
    float Aq[3][3];                   // per-slot triangular entries (off-chain)
    #pragma unroll
    for (int s = 0; s < 3; ++s)
        #pragma unroll
        for (int k = 0; k < 3; ++k) {
            wq[s][k] = __builtin_amdgcn_readlane(vcur, 62 - 3 * s - k);
            rq[s][k] = sG[wq[s][k] * 64 + lane];
        }
    // prefill A for slot 0 (groups 1,2 get theirs during groups 0,1)
    Aq[0][0] = readlane_fs(rq[0][0], wq[0][1]);  // A10
    Aq[0][1] = readlane_fs(rq[0][0], wq[0][2]);  // A20
    Aq[0][2] = readlane_fs(rq[0][1], wq[0][2]);  // A21

    #pragma unroll 1
    for (int blk = 64; blk >= 0; --blk) {
        int vnext = (blk > 0) ? seqb[(blk - 1) * 63 + lane] : vcur;
        #pragma unroll
        for (int gg = 0; gg < 21; ++gg) {      // group = steps (j, j-1, j-2)
            const int j     = 62 - 3 * gg;
            const int slot  = gg % 3;
            const int nslot = (gg + 1) % 3;
            const int wa = wq[slot][0], wb = wq[slot][1], wc = wq[slot][2];
            // ---- chain: one readlane round-trip for 3 tokens ----
            float p0 = readlane_fs(d, wa);                 // b0 = s0
            float p1 = readlane_fs(d, wb);                 // b1
            float p2 = readlane_fs(d, wc);                 // b2
            float s1v = fmaf(Aq[slot][0], p0, p1);         // s1 = b1 + A10*s0
            float s2v = fmaf(Aq[slot][1], p0, p2);         // b2 + A20*s0
            s2v = fmaf(Aq[slot][2], s1v, s2v);             // s2 += A21*s1
            d = fmaf(p0,  rq[slot][0], d);                 // d += s0*R0
            d = fmaf(s1v, rq[slot][1], d);                 // d += s1*R1
            d = fmaf(s2v, rq[slot][2], d);                 // d += s2*R2
            // ---- pack s values at lanes j, j-1, j-2 ----
            writelane_f(vS, p0, j);                        // s0 (SGPR path)
            vS = (lane == j - 1) ? __float_as_int(s1v) : vS;  // cmp+cndmask
            vS = (lane == j - 2) ? __float_as_int(s2v) : vS;
            // ---- A-extract for next group (rows arrived >= 2 groups ago) ----
            Aq[nslot][0] = readlane_fs(rq[nslot][0], wq[nslot][1]);
            Aq[nslot][1] = readlane_fs(rq[nslot][0], wq[nslot][2]);
            Aq[nslot][2] = readlane_fs(rq[nslot][1], wq[nslot][2]);
            // ---- refill this slot for group gg+3 (tokens j-9, j-10, j-11) ----
            {
                const int jb = j - 9;
                int wn0 = (jb     >= 0) ? __builtin_amdgcn_readlane(vcur, jb)
                                        : __builtin_amdgcn_readlane(vnext, jb + 63);
                int wn1 = (jb - 1 >= 0) ? __builtin_amdgcn_readlane(vcur, jb - 1)
                                        : __builtin_amdgcn_readlane(vnext, jb + 62);
                int wn2 = (jb - 2 >= 0) ? __builtin_amdgcn_readlane(vcur, jb - 2)
                                        : __builtin_amdgcn_readlane(vnext, jb + 61);
                wq[slot][0] = wn0; rq[slot][0] = sG[wn0 * 64 + lane];
                wq[slot][1] = wn1; rq[slot][1] = sG[wn1 * 64 + lane];
                wq[slot][2] = wn2; rq[slot][2] = sG[wn2 * 64 + lane];
            }
        }
        // scatter this chunk's 63 s-values into c bins (lane 63 adds 0.0)
        atomicAdd(&sc[vcur & 63], __int_as_float(vS));
        vS = 0;
        vcur = vnext;
    }
    __syncthreads();

    // ctx = sum_v c_v * key_v ; out = ctx @ Wc + bias
    float ctx = 0.f;
    #pragma unroll 8
    for (int v = 0; v < 64; ++v)
        ctx = fmaf(sc[v], keytab[v * 64 + lane], ctx);
    sCtx[lane] = ctx;
    __syncthreads();
    float o = biasv[lane];
    #pragma unroll 8
    for (int i = 0; i < 64; ++i)
        o = fmaf(sCtx[i], Wc[i * 64 + lane], o);
    out[(size_t)b * 64 + lane] = o;
}

extern "C" void kernel_launch(void* const* d_in, const int* in_sizes, int n_in,
                              void* d_out, int out_size, void* d_ws, size_t ws_size,
                              hipStream_t stream) {
    const int*   seq    = (const int*)d_in[0];
    const float* embed  = (const float*)d_in[1];
    const float* ff_w1  = (const float*)d_in[2];
    const float* ff_b1  = (const float*)d_in[3];
    const float* ff_w2  = (const float*)d_in[4];
    const float* ff_b2  = (const float*)d_in[5];
    const float* ln_w   = (const float*)d_in[6];
    const float* ln_b   = (const float*)d_in[7];
    const float* read_w = (const float*)d_in[8];
    const float* read_b = (const float*)d_in[9];
    const float* out_w  = (const float*)d_in[10];
    const float* out_b  = (const float*)d_in[11];
    float* out = (float*)d_out;

    float* wsf    = (float*)d_ws;
    float* keytab = wsf;            // 4096
    float* Gg     = wsf + 4096;     // 4096
    float* GhatN  = wsf + 8192;     // 4096
    float* Wc     = wsf + 12288;    // 4096
    float* biasv  = wsf + 16384;    // 64

    build_keys<<<64, 64, 0, stream>>>(embed, ff_w1, ff_b1, ff_w2, ff_b2, ln_w, ln_b, keytab);
    build_tables<<<64, 64, 0, stream>>>(keytab, read_w, read_b, out_w, out_b,
                                        Gg, GhatN, Wc, biasv);
    delta_scan<<<256, 64, 0, stream>>>(seq, Gg, GhatN, keytab, Wc, biasv, out);
}